// Round 10
// baseline (156.217 us; speedup 1.0000x reference)
//
#include <hip/hip_runtime.h>
#include <hip/hip_bf16.h>

// Problem constants
#define BB 4
#define NN 2048
#define DD 64
#define HH 8
#define DHH 512  // D*H

typedef __bf16 bf16_t;
typedef __bf16 bf16x8 __attribute__((ext_vector_type(8)));
typedef __bf16 bf16x4 __attribute__((ext_vector_type(4)));
typedef float f32x4 __attribute__((ext_vector_type(4)));
typedef long long i64;
typedef i64 i64x2 __attribute__((ext_vector_type(2)));
typedef _Float16 f16_t;
typedef _Float16 f16x4 __attribute__((ext_vector_type(4)));
typedef __fp16 h16x2 __attribute__((ext_vector_type(2)));   // cvt_pkrtz native type

// Async global->LDS, 16B per lane (used by qkv/out_proj staging only).
__device__ __forceinline__ void dma16(const void* g, void* l) {
    __builtin_amdgcn_global_load_lds(
        (const __attribute__((address_space(1))) unsigned int*)g,
        (__attribute__((address_space(3))) unsigned int*)l,
        16, 0, 0);
}

#define MFMA   __builtin_amdgcn_mfma_f32_16x16x32_bf16
#define MFMA8  __builtin_amdgcn_mfma_f32_16x16x32_fp8_fp8
#define MFMA16F __builtin_amdgcn_mfma_f32_16x16x16f16

// q-scale 1/sqrt(64) with log2(e) folded in (softmax via exp2)
#define QSCALE 0.18033688011112042f

// fp8 q/k row layout (64 bytes per (b,h,n)): logical element d lives at byte
//   phys(d) = (d&7) + (d>>5)*8 + (((d>>3)&3) ^ (n&3))*16
// One b128 read at granule (quad ^ (n&3)) yields BOTH K=32 fp8 MFMA frags
// for a lane (i64x2: .x = k-lo, .y = k-hi).

// -------------------------------------------------------------------------
// Kernel P: prep (unchanged R8). Wqt/Wkt/Wvt [512][64] bf16 (QSCALE in Wqt),
// Wut [64][512] bf16. 16 blocks.
// -------------------------------------------------------------------------
__global__ __launch_bounds__(256) void prep(
    const float* __restrict__ Wq, const float* __restrict__ Wk,
    const float* __restrict__ Wv, const float* __restrict__ Wu,
    bf16_t* __restrict__ Wqt, bf16_t* __restrict__ Wkt,
    bf16_t* __restrict__ Wvt, bf16_t* __restrict__ Wut)
{
    const int bid = blockIdx.x, tid = threadIdx.x;
    if (bid < 12) {
        const int m = bid >> 2, slice = bid & 3;
        const float* src = (m == 0) ? Wq : (m == 1) ? Wk : Wv;
        bf16_t* dst = (m == 0) ? Wqt : (m == 1) ? Wkt : Wvt;
        const float scale = (m == 0) ? QSCALE : 1.0f;
        const int dc = slice * 128 + (tid >> 1);
        const int kbase = (tid & 1) * 32;
        #pragma unroll
        for (int k0 = 0; k0 < 4; ++k0) {
            bf16x8 p;
            #pragma unroll
            for (int j = 0; j < 8; ++j)
                p[j] = (bf16_t)(src[(size_t)(kbase + k0 * 8 + j) * 512 + dc] * scale);
            *(bf16x8*)(dst + dc * 64 + kbase + k0 * 8) = p;
        }
    } else {
        const int kq = (bid - 12) * 128;
        const int dc = tid >> 2, sub = (tid & 3) * 32;
        #pragma unroll
        for (int k0 = 0; k0 < 4; ++k0) {
            bf16x8 p;
            #pragma unroll
            for (int j = 0; j < 8; ++j)
                p[j] = (bf16_t)Wu[(size_t)(kq + sub + k0 * 8 + j) * 64 + dc];
            *(bf16x8*)(Wut + dc * 512 + kq + sub + k0 * 8) = p;
        }
    }
}

// -------------------------------------------------------------------------
// Kernel A: QKV via MFMA (R8 structure). q,k -> fp8 e4m3 packed layout;
// vt -> f16 [b,h,d,n] (f16 feeds the 16x16x16f16 PV MFMA).
// -------------------------------------------------------------------------
__global__ __launch_bounds__(256) void qkv_mfma(
    const float* __restrict__ x, const bf16_t* __restrict__ Wqt,
    const bf16_t* __restrict__ Wkt, const bf16_t* __restrict__ Wvt,
    char* __restrict__ q8, char* __restrict__ k8, f16_t* __restrict__ vt)
{
    const int n0   = blockIdx.x * 64;
    const int h    = blockIdx.y;
    const int tid  = threadIdx.x;
    const int w    = tid >> 6;
    const int lane = tid & 63;
    const int quad = lane >> 4;
    const int c    = lane & 15;
    const int cq   = c & 7;
    const int l8   = lane >> 3;
    const int lg   = (lane & 7) ^ l8;
    const int lo   = l8 * 128 + lg * 16;
    const int sw0  = ((quad    ) ^ cq) * 16;
    const int sw1  = ((quad + 4) ^ cq) * 16;
    const int w2048 = w * 2048;

    __shared__ __align__(16) float  xs[64 * 64];   // 16KB [row][256B], swizzled
    __shared__ __align__(16) bf16_t Wqs[64 * 64], Wks[64 * 64], Wvs[64 * 64];

    {
        const int rloc = lane >> 4;
        const int s    = lane & 15;
        #pragma unroll
        for (int j = 0; j < 4; ++j) {
            int chunk = w * 4 + j;
            int r7 = (chunk * 4 + rloc) & 7;
            const char* src = (const char*)(x + (size_t)(n0 + chunk * 4 + rloc) * 64)
                            + ((s & 8) | ((s & 7) ^ r7)) * 16;
            dma16(src, (char*)xs + chunk * 1024);
        }
    }
    const char* qg = (const char*)Wqt + (size_t)h * 8192;
    const char* kg = (const char*)Wkt + (size_t)h * 8192;
    const char* vg = (const char*)Wvt + (size_t)h * 8192;
    dma16(qg + w2048 + lo,        (char*)Wqs + w2048);
    dma16(qg + w2048 + 1024 + lo, (char*)Wqs + w2048 + 1024);
    dma16(kg + w2048 + lo,        (char*)Wks + w2048);
    dma16(kg + w2048 + 1024 + lo, (char*)Wks + w2048 + 1024);
    dma16(vg + w2048 + lo,        (char*)Wvs + w2048);
    dma16(vg + w2048 + 1024 + lo, (char*)Wvs + w2048 + 1024);
    __syncthreads();

    auto xfrag = [&](int row, int kk) -> bf16x8 {
        const char* rbase = (const char*)xs + row * 256;
        int g0 = kk * 8 + ((quad * 2    ) ^ cq);
        int g1 = kk * 8 + ((quad * 2 + 1) ^ cq);
        f32x4 a = *(const f32x4*)(rbase + g0 * 16);
        f32x4 b = *(const f32x4*)(rbase + g1 * 16);
        bf16x8 r;
        r[0] = (bf16_t)a[0]; r[1] = (bf16_t)a[1]; r[2] = (bf16_t)a[2]; r[3] = (bf16_t)a[3];
        r[4] = (bf16_t)b[0]; r[5] = (bf16_t)b[1]; r[6] = (bf16_t)b[2]; r[7] = (bf16_t)b[3];
        return r;
    };

    bf16x8 xf0 = xfrag(w * 16 + c, 0);
    bf16x8 xf1 = xfrag(w * 16 + c, 1);

    const int gr = n0 + w * 16 + c;
    const int bb = gr >> 11, nn = gr & 2047;
    char* qrow_g = q8 + (((size_t)bb * HH + h) * NN + nn) * 64;
    char* krow_g = k8 + (((size_t)bb * HH + h) * NN + nn) * 64;
    const int nsw = nn & 3;

    #pragma unroll
    for (int mb = 0; mb < 4; ++mb) {
        const char* aq = (const char*)Wqs + (mb * 16 + c) * 128;
        const char* ak = (const char*)Wks + (mb * 16 + c) * 128;
        f32x4 accq = (f32x4){0.f, 0.f, 0.f, 0.f};
        f32x4 acck = (f32x4){0.f, 0.f, 0.f, 0.f};
        accq = MFMA(*(const bf16x8*)(aq + sw0), xf0, accq, 0, 0, 0);
        accq = MFMA(*(const bf16x8*)(aq + sw1), xf1, accq, 0, 0, 0);
        acck = MFMA(*(const bf16x8*)(ak + sw0), xf0, acck, 0, 0, 0);
        acck = MFMA(*(const bf16x8*)(ak + sw1), xf1, acck, 0, 0, 0);
        int g2  = (mb * 2 + (quad >> 1)) & 3;
        int off = ((quad & 1) * 4) + ((mb >> 1) * 8) + ((g2 ^ nsw) * 16);
        int pq = __builtin_amdgcn_cvt_pk_fp8_f32(accq[0], accq[1], 0, false);
        pq     = __builtin_amdgcn_cvt_pk_fp8_f32(accq[2], accq[3], pq, true);
        int pk = __builtin_amdgcn_cvt_pk_fp8_f32(acck[0], acck[1], 0, false);
        pk     = __builtin_amdgcn_cvt_pk_fp8_f32(acck[2], acck[3], pk, true);
        *(int*)(qrow_g + off) = pq;
        *(int*)(krow_g + off) = pk;
    }

    const char* wvrow = (const char*)Wvs + (w * 16 + c) * 128;
    bf16x8 vf0 = *(const bf16x8*)(wvrow + sw0);
    bf16x8 vf1 = *(const bf16x8*)(wvrow + sw1);

    const int bb2 = n0 >> 11;
    f16_t* vtrow_g = vt + (((size_t)bb2 * HH + h) * DD + (w * 16 + c)) * NN + (n0 & 2047);

    #pragma unroll
    for (int nb = 0; nb < 4; ++nb) {
        f32x4 acc = (f32x4){0.f, 0.f, 0.f, 0.f};
        acc = MFMA(xfrag(nb * 16 + c, 0), vf0, acc, 0, 0, 0);
        acc = MFMA(xfrag(nb * 16 + c, 1), vf1, acc, 0, 0, 0);
        f16x4 p = { (f16_t)acc[0], (f16_t)acc[1], (f16_t)acc[2], (f16_t)acc[3] };
        *(f16x4*)(vtrow_g + nb * 16 + quad * 4) = p;
    }
}

// -------------------------------------------------------------------------
// Kernel B: flash attention, KEY-SPLIT waves. Wave w owns keys w*16..+15 of
// each 64-key tile, computing S^T for ALL 64 q-cols; the S C-layout
// (col=q, row=key quad*4+r) IS the 16x16x16f16 B-frag layout, so P stays in
// registers (exp2 -> cvt_pkrtz -> PV MFMA). K (fp8, 1 b128) and V (f16,
// 4 b64) frags are wave-private -> read DIRECT from global (L2-resident via
// head-first grid) with distance-1 register prefetch. NO LDS / NO barriers
// in the K-loop. Epilogue: cross-wave O reduction via 16KB LDS.
// -------------------------------------------------------------------------
__global__ __launch_bounds__(256, 4) void flash_attn(
    const char* __restrict__ q8, const char* __restrict__ k8,
    const f16_t* __restrict__ vt, bf16_t* __restrict__ y)
{
    const int h    = blockIdx.x;          // head first -> XCD L2 locality
    const int n0   = blockIdx.y * 64;
    const int b    = blockIdx.z;
    const int tid  = threadIdx.x;
    const int w    = tid >> 6;
    const int lane = tid & 63;
    const int quad = lane >> 4;
    const int c    = lane & 15;
    const int ksw  = (quad ^ (c & 3)) * 16;   // fp8 granule slot

    __shared__ __align__(16) char LB[17408];  // Ob 16KB + Lb 1KB (epilogue only)

    const size_t bh = (size_t)(b * HH + h);
    const char* qp = q8 + bh * (size_t)(NN * 64);
    const char* kp = k8 + bh * (size_t)(NN * 64);
    const char* vp = (const char*)(vt + bh * (size_t)(DD * NN));

    // Q B-frags (fp8 packed): q-rows n0 + cb*16 + c, once from global
    i64x2 qf[4];
    #pragma unroll
    for (int cb = 0; cb < 4; ++cb)
        qf[cb] = *(const i64x2*)(qp + (size_t)(n0 + cb * 16 + c) * 64 + ksw);

    // per-lane streaming bases
    const char* kfp = kp + (size_t)(w * 16 + c) * 64 + ksw;        // +kt*4096
    const char* vfp = vp + (size_t)c * 4096 + w * 32 + quad * 8;   // +db*65536 +kt*128

    // tile-0 operand frags
    i64x2 kf = *(const i64x2*)(kfp);
    f16x4 vf[4];
    #pragma unroll
    for (int db = 0; db < 4; ++db)
        vf[db] = *(const f16x4*)(vfp + db * 65536);

    float lsum[4] = {0.f, 0.f, 0.f, 0.f};
    f32x4 o[4][4];   // o[db][cb]: O^T[d=db*16+quad*4+r][q=cb*16+c]
    #pragma unroll
    for (int db = 0; db < 4; ++db)
        #pragma unroll
        for (int cb = 0; cb < 4; ++cb) o[db][cb] = (f32x4){0.f, 0.f, 0.f, 0.f};

    for (int kt = 0; kt < 32; ++kt) {
        // distance-1 register prefetch (wraps on last iter; harmless)
        const int kt2 = (kt + 1) & 31;
        i64x2 kf_n = *(const i64x2*)(kfp + (size_t)kt2 * 4096);
        f16x4 vf_n[4];
        #pragma unroll
        for (int db = 0; db < 4; ++db)
            vf_n[db] = *(const f16x4*)(vfp + db * 65536 + (size_t)kt2 * 128);

        // per q-col-block: S^T (fp8) -> exp2 -> register P -> PV (f16 k=16)
        #pragma unroll
        for (int cb = 0; cb < 4; ++cb) {
            f32x4 s = (f32x4){0.f, 0.f, 0.f, 0.f};
            s = MFMA8(kf.x, qf[cb].x, s, 0, 0, 0);
            s = MFMA8(kf.y, qf[cb].y, s, 0, 0, 0);
            float p0 = __builtin_amdgcn_exp2f(s[0]);
            float p1 = __builtin_amdgcn_exp2f(s[1]);
            float p2 = __builtin_amdgcn_exp2f(s[2]);
            float p3 = __builtin_amdgcn_exp2f(s[3]);
            lsum[cb] += (p0 + p1) + (p2 + p3);
            h16x2 ab = __builtin_amdgcn_cvt_pkrtz(p0, p1);
            h16x2 cd = __builtin_amdgcn_cvt_pkrtz(p2, p3);
            f16x4 pf = { (f16_t)ab[0], (f16_t)ab[1], (f16_t)cd[0], (f16_t)cd[1] };
            #pragma unroll
            for (int db = 0; db < 4; ++db)
                o[db][cb] = MFMA16F(vf[db], pf, o[db][cb], 0, 0, 0);
        }

        kf = kf_n;
        #pragma unroll
        for (int db = 0; db < 4; ++db) vf[db] = vf_n[db];
    }

    // ---- epilogue: cross-wave reduction ----
    char* Ob = LB;            // 16KB: slot ((db*4+cb)*4+quad)*16 + c, f32x4
    float* Lb = (float*)(LB + 16384);   // [w][cb][c] partial lsums

    // lsum: reduce over quads (xor 16,32), then one lane-row writes
    #pragma unroll
    for (int cb = 0; cb < 4; ++cb) {
        lsum[cb] += __shfl_xor(lsum[cb], 16, 64);
        lsum[cb] += __shfl_xor(lsum[cb], 32, 64);
    }
    if (quad == 0) {
        #pragma unroll
        for (int cb = 0; cb < 4; ++cb)
            Lb[(w * 4 + cb) * 16 + c] = lsum[cb];
    }

    // O: sequential accumulate across waves (LDS unused during the loop)
    #pragma unroll
    for (int ww = 0; ww < 4; ++ww) {
        if (w == ww) {
            #pragma unroll
            for (int db = 0; db < 4; ++db) {
                #pragma unroll
                for (int cb = 0; cb < 4; ++cb) {
                    char* p = Ob + (size_t)(((db * 4 + cb) * 4 + quad) * 16 + c) * 16;
                    f32x4 v = o[db][cb];
                    if (ww > 0) v += *(const f32x4*)p;
                    *(f32x4*)p = v;
                }
            }
        }
        __syncthreads();
    }

    // readout: thread t -> q-row n_loc = t&63, d-quarter dq = t>>6
    {
        const int n_loc = tid & 63;
        const int dq    = tid >> 6;
        const int qcb   = n_loc >> 4;
        const int cc    = n_loc & 15;
        float l = Lb[(0 * 4 + qcb) * 16 + cc] + Lb[(1 * 4 + qcb) * 16 + cc]
                + Lb[(2 * 4 + qcb) * 16 + cc] + Lb[(3 * 4 + qcb) * 16 + cc];
        float inv = 1.0f / l;
        float vals[16];
        #pragma unroll
        for (int q2 = 0; q2 < 4; ++q2) {
            f32x4 v = *(const f32x4*)(Ob
                    + (size_t)(((dq * 4 + qcb) * 4 + q2) * 16 + cc) * 16);
            vals[q2 * 4 + 0] = v[0]; vals[q2 * 4 + 1] = v[1];
            vals[q2 * 4 + 2] = v[2]; vals[q2 * 4 + 3] = v[3];
        }
        bf16x8 o0, o1;
        #pragma unroll
        for (int j = 0; j < 8; ++j) {
            o0[j] = (bf16_t)(vals[j] * inv);
            o1[j] = (bf16_t)(vals[8 + j] * inv);
        }
        bf16_t* yrow = y + bh * (size_t)(NN * DD) + (size_t)(n0 + n_loc) * DD + dq * 16;
        *(bf16x8*)(yrow)     = o0;
        *(bf16x8*)(yrow + 8) = o1;
    }
}

// -------------------------------------------------------------------------
// Kernel C: output projection via MFMA (unchanged R8). 512 blocks.
// -------------------------------------------------------------------------
__global__ __launch_bounds__(256) void out_proj(
    const bf16_t* __restrict__ y,    // [b,h,n,d] bf16
    const bf16_t* __restrict__ Wut,  // [64][512]
    const float* __restrict__ bu, float* __restrict__ out)
{
    const int rt   = blockIdx.x >> 1;
    const int dh   = blockIdx.x & 1;
    const int row0 = rt * 32;
    const int b    = row0 >> 11;
    const int nn0  = row0 & 2047;
    const int tid  = threadIdx.x;
    const int w    = tid >> 6;
    const int lane = tid & 63;
    const int quad = lane >> 4;
    const int c    = lane & 15;
    const int cq   = c & 7;

    __shared__ __align__(16) bf16_t ys[32 * 512];   // 32KB [row][1024B], swizzled

    {
        const int hsel = lane >> 3;
        const int g7   = lane & 7;
        #pragma unroll
        for (int rr = 0; rr < 8; ++rr) {
            int row = w * 8 + rr;
            const char* src = (const char*)y
                + (((size_t)b * HH + hsel) * NN + nn0 + row) * 128
                + ((g7 ^ (row & 7)) * 16);
            dma16(src, (char*)ys + row * 1024);
        }
    }
    __syncthreads();

    const int rows16 = (w >> 1) * 16;
    const int mb     = dh * 2 + (w & 1);
    const char* yrow = (const char*)ys + (rows16 + c) * 1024;

    f32x4 acc = (f32x4){0.f, 0.f, 0.f, 0.f};
    #pragma unroll
    for (int kk = 0; kk < 16; ++kk) {
        int g = kk * 4 + quad;
        bf16x8 bfrag = *(const bf16x8*)(yrow + (((g & ~7) | ((g & 7) ^ cq)) * 16));
        bf16x8 afrag = *(const bf16x8*)((const char*)Wut
                        + (size_t)(mb * 16 + c) * 1024 + kk * 64 + quad * 16);
        acc = MFMA(afrag, bfrag, acc, 0, 0, 0);
    }

    float4 bb = *(const float4*)(bu + mb * 16 + quad * 4);
    float4 res = { acc[0] + bb.x, acc[1] + bb.y, acc[2] + bb.z, acc[3] + bb.w };
    float* op = out + (size_t)(row0 + rows16 + c) * DD + mb * 16 + quad * 4;
    *(float4*)op = res;
}

// -------------------------------------------------------------------------
extern "C" void kernel_launch(void* const* d_in, const int* in_sizes, int n_in,
                              void* d_out, int out_size, void* d_ws, size_t ws_size,
                              hipStream_t stream) {
    const float* x  = (const float*)d_in[0];
    const float* Wq = (const float*)d_in[1];
    const float* Wk = (const float*)d_in[2];
    const float* Wv = (const float*)d_in[3];
    const float* Wu = (const float*)d_in[4];
    const float* bu = (const float*)d_in[5];
    float* out = (float*)d_out;

    // workspace: q8 4M | k8 4M | vt 8M (f16) | y 8M (bf16) | weights 64K x4
    const size_t SEG8 = (size_t)BB * HH * NN * 64;   // 4 MiB (fp8 rows)
    const size_t SEG  = SEG8 * 2;                    // 8 MiB
    char* ws = (char*)d_ws;
    char*   q8  = ws;
    char*   k8  = ws + SEG8;
    f16_t*  vt  = (f16_t*)(ws + 2 * SEG8);
    bf16_t* y   = (bf16_t*)(ws + 2 * SEG8 + SEG);
    bf16_t* Wqt = (bf16_t*)(ws + 2 * SEG8 + 2 * SEG);
    bf16_t* Wkt = (bf16_t*)(ws + 2 * SEG8 + 2 * SEG + (1 << 16));
    bf16_t* Wvt = (bf16_t*)(ws + 2 * SEG8 + 2 * SEG + 2 * (1 << 16));
    bf16_t* Wut = (bf16_t*)(ws + 2 * SEG8 + 2 * SEG + 3 * (1 << 16));

    prep<<<dim3(16), dim3(256), 0, stream>>>(Wq, Wk, Wv, Wu, Wqt, Wkt, Wvt, Wut);
    qkv_mfma<<<dim3(128, 8), dim3(256), 0, stream>>>(x, Wqt, Wkt, Wvt, q8, k8, vt);
    flash_attn<<<dim3(HH, NN / 64, BB), dim3(256), 0, stream>>>(q8, k8, vt, y);
    out_proj<<<dim3(512), dim3(256), 0, stream>>>(y, Wut, bu, out);
}

// Round 11
// 129.036 us; speedup vs baseline: 1.2107x; 1.2107x over previous
//
#include <hip/hip_runtime.h>
#include <hip/hip_bf16.h>

// Problem constants
#define BB 4
#define NN 2048
#define DD 64
#define HH 8
#define DHH 512  // D*H

typedef __bf16 bf16_t;
typedef __bf16 bf16x8 __attribute__((ext_vector_type(8)));
typedef __bf16 bf16x4 __attribute__((ext_vector_type(4)));
typedef float f32x4 __attribute__((ext_vector_type(4)));
typedef long long i64;
typedef i64 i64x2 __attribute__((ext_vector_type(2)));
typedef _Float16 f16_t;
typedef _Float16 f16x4 __attribute__((ext_vector_type(4)));
typedef __fp16 h16x2 __attribute__((ext_vector_type(2)));   // cvt_pkrtz native type

// Async global->LDS, 16B per lane. HW places lane i at (wave-uniform base) + i*16.
__device__ __forceinline__ void dma16(const void* g, void* l) {
    __builtin_amdgcn_global_load_lds(
        (const __attribute__((address_space(1))) unsigned int*)g,
        (__attribute__((address_space(3))) unsigned int*)l,
        16, 0, 0);
}

#define MFMA   __builtin_amdgcn_mfma_f32_16x16x32_bf16
#define MFMA8  __builtin_amdgcn_mfma_f32_16x16x32_fp8_fp8
#define MFMA16F __builtin_amdgcn_mfma_f32_16x16x16f16

// q-scale 1/sqrt(64) with log2(e) folded in (softmax via exp2)
#define QSCALE 0.18033688011112042f

// fp8 q/k row layout (64 bytes per (b,h,n)): logical element d lives at byte
//   phys(d) = (d&7) + (d>>5)*8 + (((d>>3)&3) ^ (n&3))*16
// One b128 read at granule (quad ^ (n&3)) yields BOTH K=32 fp8 MFMA frags
// for a lane (i64x2: .x = k-lo, .y = k-hi).

// -------------------------------------------------------------------------
// Kernel P: prep (unchanged). Wqt/Wkt/Wvt [512][64] bf16 (QSCALE in Wqt),
// Wut [64][512] bf16. 16 blocks.
// -------------------------------------------------------------------------
__global__ __launch_bounds__(256) void prep(
    const float* __restrict__ Wq, const float* __restrict__ Wk,
    const float* __restrict__ Wv, const float* __restrict__ Wu,
    bf16_t* __restrict__ Wqt, bf16_t* __restrict__ Wkt,
    bf16_t* __restrict__ Wvt, bf16_t* __restrict__ Wut)
{
    const int bid = blockIdx.x, tid = threadIdx.x;
    if (bid < 12) {
        const int m = bid >> 2, slice = bid & 3;
        const float* src = (m == 0) ? Wq : (m == 1) ? Wk : Wv;
        bf16_t* dst = (m == 0) ? Wqt : (m == 1) ? Wkt : Wvt;
        const float scale = (m == 0) ? QSCALE : 1.0f;
        const int dc = slice * 128 + (tid >> 1);
        const int kbase = (tid & 1) * 32;
        #pragma unroll
        for (int k0 = 0; k0 < 4; ++k0) {
            bf16x8 p;
            #pragma unroll
            for (int j = 0; j < 8; ++j)
                p[j] = (bf16_t)(src[(size_t)(kbase + k0 * 8 + j) * 512 + dc] * scale);
            *(bf16x8*)(dst + dc * 64 + kbase + k0 * 8) = p;
        }
    } else {
        const int kq = (bid - 12) * 128;
        const int dc = tid >> 2, sub = (tid & 3) * 32;
        #pragma unroll
        for (int k0 = 0; k0 < 4; ++k0) {
            bf16x8 p;
            #pragma unroll
            for (int j = 0; j < 8; ++j)
                p[j] = (bf16_t)Wu[(size_t)(kq + sub + k0 * 8 + j) * 64 + dc];
            *(bf16x8*)(Wut + dc * 512 + kq + sub + k0 * 8) = p;
        }
    }
}

// -------------------------------------------------------------------------
// Kernel A: QKV via MFMA (unchanged). q,k -> fp8 e4m3 packed layout;
// vt -> f16 [b,h,d,n].
// -------------------------------------------------------------------------
__global__ __launch_bounds__(256) void qkv_mfma(
    const float* __restrict__ x, const bf16_t* __restrict__ Wqt,
    const bf16_t* __restrict__ Wkt, const bf16_t* __restrict__ Wvt,
    char* __restrict__ q8, char* __restrict__ k8, f16_t* __restrict__ vt)
{
    const int n0   = blockIdx.x * 64;
    const int h    = blockIdx.y;
    const int tid  = threadIdx.x;
    const int w    = tid >> 6;
    const int lane = tid & 63;
    const int quad = lane >> 4;
    const int c    = lane & 15;
    const int cq   = c & 7;
    const int l8   = lane >> 3;
    const int lg   = (lane & 7) ^ l8;
    const int lo   = l8 * 128 + lg * 16;
    const int sw0  = ((quad    ) ^ cq) * 16;
    const int sw1  = ((quad + 4) ^ cq) * 16;
    const int w2048 = w * 2048;

    __shared__ __align__(16) float  xs[64 * 64];   // 16KB [row][256B], swizzled
    __shared__ __align__(16) bf16_t Wqs[64 * 64], Wks[64 * 64], Wvs[64 * 64];

    {
        const int rloc = lane >> 4;
        const int s    = lane & 15;
        #pragma unroll
        for (int j = 0; j < 4; ++j) {
            int chunk = w * 4 + j;
            int r7 = (chunk * 4 + rloc) & 7;
            const char* src = (const char*)(x + (size_t)(n0 + chunk * 4 + rloc) * 64)
                            + ((s & 8) | ((s & 7) ^ r7)) * 16;
            dma16(src, (char*)xs + chunk * 1024);
        }
    }
    const char* qg = (const char*)Wqt + (size_t)h * 8192;
    const char* kg = (const char*)Wkt + (size_t)h * 8192;
    const char* vg = (const char*)Wvt + (size_t)h * 8192;
    dma16(qg + w2048 + lo,        (char*)Wqs + w2048);
    dma16(qg + w2048 + 1024 + lo, (char*)Wqs + w2048 + 1024);
    dma16(kg + w2048 + lo,        (char*)Wks + w2048);
    dma16(kg + w2048 + 1024 + lo, (char*)Wks + w2048 + 1024);
    dma16(vg + w2048 + lo,        (char*)Wvs + w2048);
    dma16(vg + w2048 + 1024 + lo, (char*)Wvs + w2048 + 1024);
    __syncthreads();

    auto xfrag = [&](int row, int kk) -> bf16x8 {
        const char* rbase = (const char*)xs + row * 256;
        int g0 = kk * 8 + ((quad * 2    ) ^ cq);
        int g1 = kk * 8 + ((quad * 2 + 1) ^ cq);
        f32x4 a = *(const f32x4*)(rbase + g0 * 16);
        f32x4 b = *(const f32x4*)(rbase + g1 * 16);
        bf16x8 r;
        r[0] = (bf16_t)a[0]; r[1] = (bf16_t)a[1]; r[2] = (bf16_t)a[2]; r[3] = (bf16_t)a[3];
        r[4] = (bf16_t)b[0]; r[5] = (bf16_t)b[1]; r[6] = (bf16_t)b[2]; r[7] = (bf16_t)b[3];
        return r;
    };

    bf16x8 xf0 = xfrag(w * 16 + c, 0);
    bf16x8 xf1 = xfrag(w * 16 + c, 1);

    const int gr = n0 + w * 16 + c;
    const int bb = gr >> 11, nn = gr & 2047;
    char* qrow_g = q8 + (((size_t)bb * HH + h) * NN + nn) * 64;
    char* krow_g = k8 + (((size_t)bb * HH + h) * NN + nn) * 64;
    const int nsw = nn & 3;

    #pragma unroll
    for (int mb = 0; mb < 4; ++mb) {
        const char* aq = (const char*)Wqs + (mb * 16 + c) * 128;
        const char* ak = (const char*)Wks + (mb * 16 + c) * 128;
        f32x4 accq = (f32x4){0.f, 0.f, 0.f, 0.f};
        f32x4 acck = (f32x4){0.f, 0.f, 0.f, 0.f};
        accq = MFMA(*(const bf16x8*)(aq + sw0), xf0, accq, 0, 0, 0);
        accq = MFMA(*(const bf16x8*)(aq + sw1), xf1, accq, 0, 0, 0);
        acck = MFMA(*(const bf16x8*)(ak + sw0), xf0, acck, 0, 0, 0);
        acck = MFMA(*(const bf16x8*)(ak + sw1), xf1, acck, 0, 0, 0);
        int g2  = (mb * 2 + (quad >> 1)) & 3;
        int off = ((quad & 1) * 4) + ((mb >> 1) * 8) + ((g2 ^ nsw) * 16);
        int pq = __builtin_amdgcn_cvt_pk_fp8_f32(accq[0], accq[1], 0, false);
        pq     = __builtin_amdgcn_cvt_pk_fp8_f32(accq[2], accq[3], pq, true);
        int pk = __builtin_amdgcn_cvt_pk_fp8_f32(acck[0], acck[1], 0, false);
        pk     = __builtin_amdgcn_cvt_pk_fp8_f32(acck[2], acck[3], pk, true);
        *(int*)(qrow_g + off) = pq;
        *(int*)(krow_g + off) = pk;
    }

    const char* wvrow = (const char*)Wvs + (w * 16 + c) * 128;
    bf16x8 vf0 = *(const bf16x8*)(wvrow + sw0);
    bf16x8 vf1 = *(const bf16x8*)(wvrow + sw1);

    const int bb2 = n0 >> 11;
    f16_t* vtrow_g = vt + (((size_t)bb2 * HH + h) * DD + (w * 16 + c)) * NN + (n0 & 2047);

    #pragma unroll
    for (int nb = 0; nb < 4; ++nb) {
        f32x4 acc = (f32x4){0.f, 0.f, 0.f, 0.f};
        acc = MFMA(xfrag(nb * 16 + c, 0), vf0, acc, 0, 0, 0);
        acc = MFMA(xfrag(nb * 16 + c, 1), vf1, acc, 0, 0, 0);
        f16x4 p = { (f16_t)acc[0], (f16_t)acc[1], (f16_t)acc[2], (f16_t)acc[3] };
        *(f16x4*)(vtrow_g + nb * 16 + quad * 4) = p;
    }
}

// -------------------------------------------------------------------------
// Kernel B: flash attention — R10 key-split register-P compute core fed by
// R8's DMA double-buffer (no in-loop global latency exposure).
// Wave w owns keys w*16..+15 per 64-key tile for all 64 q-cols; S^T C-layout
// = f16 16x16x16 B-frag layout -> P stays in registers. Per wave-tile LDS:
// 1 ds_read_b128 (K fp8) + 4 ds_read_b64 (V f16) + 3 dma16.
// LDS 24KB in-loop (K dbuf 8 + V dbuf 16), overlaid epilogue buffer.
// -------------------------------------------------------------------------
__global__ __launch_bounds__(256, 4) void flash_attn(
    const char* __restrict__ q8, const char* __restrict__ k8,
    const f16_t* __restrict__ vt, bf16_t* __restrict__ y)
{
    const int h    = blockIdx.x;          // head first -> XCD L2 locality
    const int n0   = blockIdx.y * 64;
    const int b    = blockIdx.z;
    const int tid  = threadIdx.x;
    const int w    = tid >> 6;
    const int lane = tid & 63;
    const int quad = lane >> 4;
    const int c    = lane & 15;
    const int l8   = lane >> 3;
    const int lg   = (lane & 7) ^ l8;
    const int ksw  = (quad ^ (c & 3)) * 16;   // fp8 granule slot

    __shared__ __align__(16) char SM[24576];
    // in-loop: Ks dbuf SM[0..8K), Vs dbuf SM[8K..24K); epilogue: Ob SM[0..16K), Lb SM[16K..17K)

    const size_t bh = (size_t)(b * HH + h);
    const char* qp = q8 + bh * (size_t)(NN * 64);
    const char* kp = k8 + bh * (size_t)(NN * 64);
    const char* vp = (const char*)(vt + bh * (size_t)(DD * NN));

    // Q B-frags (fp8 packed): issued before any DMA
    i64x2 qf[4];
    #pragma unroll
    for (int cb = 0; cb < 4; ++cb)
        qf[cb] = *(const i64x2*)(qp + (size_t)(n0 + cb * 16 + c) * 64 + ksw);

    // DMA source lane pointers
    const char* kdma = kp + w * 1024 + lane * 16;              // + kt*4096
    const char* vdma = vp + (size_t)(w * 16 + l8) * 4096 + lg * 16;  // + kt*128; +32768 for 2nd
    // LDS read offsets
    const int kro = (w * 16 + c) * 64 + ksw;                   // K frag (b128)
    const int vro = c * 128 + (((w * 2 + (quad >> 1)) ^ (c & 7)) * 16) + (quad & 1) * 8;

    // ---- prologue: tile-0 DMA ----
    dma16(kdma,          SM + w * 1024);
    dma16(vdma,          SM + 8192 + w * 2048);
    dma16(vdma + 32768,  SM + 8192 + w * 2048 + 1024);

    float lsum[4] = {0.f, 0.f, 0.f, 0.f};
    f32x4 o[4][4];   // o[db][cb]: O^T[d=db*16+quad*4+r][q=cb*16+c]
    #pragma unroll
    for (int db = 0; db < 4; ++db)
        #pragma unroll
        for (int cb = 0; cb < 4; ++cb) o[db][cb] = (f32x4){0.f, 0.f, 0.f, 0.f};

    __syncthreads();   // tile-0 drained

    // stage tile 1 (buf 1)
    dma16(kdma + 4096,          SM + 4096 + w * 1024);
    dma16(vdma + 128,           SM + 16384 + w * 2048);
    dma16(vdma + 128 + 32768,   SM + 16384 + w * 2048 + 1024);

    for (int kt = 0; kt < 32; ++kt) {
        const int buf = kt & 1;
        if (kt > 0) {
            __syncthreads();
            if (kt < 31) {
                const size_t adv = (size_t)(kt + 1);
                dma16(kdma + adv * 4096,         SM + (buf ^ 1) * 4096 + w * 1024);
                dma16(vdma + adv * 128,          SM + 8192 + (buf ^ 1) * 8192 + w * 2048);
                dma16(vdma + adv * 128 + 32768,  SM + 8192 + (buf ^ 1) * 8192 + w * 2048 + 1024);
            }
        }
        const char* kb = SM + buf * 4096;
        const char* vb = SM + 8192 + buf * 8192;

        // operand frags from LDS (wave-private slices)
        i64x2 kf = *(const i64x2*)(kb + kro);
        f16x4 vf[4];
        #pragma unroll
        for (int db = 0; db < 4; ++db)
            vf[db] = *(const f16x4*)(vb + vro + db * 2048);

        // per q-col-block: S^T (fp8) -> exp2 -> register P -> PV (f16 k=16)
        #pragma unroll
        for (int cb = 0; cb < 4; ++cb) {
            f32x4 s = (f32x4){0.f, 0.f, 0.f, 0.f};
            s = MFMA8(kf.x, qf[cb].x, s, 0, 0, 0);
            s = MFMA8(kf.y, qf[cb].y, s, 0, 0, 0);
            float p0 = __builtin_amdgcn_exp2f(s[0]);
            float p1 = __builtin_amdgcn_exp2f(s[1]);
            float p2 = __builtin_amdgcn_exp2f(s[2]);
            float p3 = __builtin_amdgcn_exp2f(s[3]);
            lsum[cb] += (p0 + p1) + (p2 + p3);
            h16x2 ab = __builtin_amdgcn_cvt_pkrtz(p0, p1);
            h16x2 cd = __builtin_amdgcn_cvt_pkrtz(p2, p3);
            f16x4 pf = { (f16_t)ab[0], (f16_t)ab[1], (f16_t)cd[0], (f16_t)cd[1] };
            #pragma unroll
            for (int db = 0; db < 4; ++db)
                o[db][cb] = MFMA16F(vf[db], pf, o[db][cb], 0, 0, 0);
        }
    }

    __syncthreads();   // all tile-31 LDS reads done before overlay reuse

    // ---- epilogue: cross-wave reduction (Ob = SM[0..16K), Lb = SM+16K) ----
    char*  Ob = SM;
    float* Lb = (float*)(SM + 16384);

    #pragma unroll
    for (int cb = 0; cb < 4; ++cb) {
        lsum[cb] += __shfl_xor(lsum[cb], 16, 64);
        lsum[cb] += __shfl_xor(lsum[cb], 32, 64);
    }
    if (quad == 0) {
        #pragma unroll
        for (int cb = 0; cb < 4; ++cb)
            Lb[(w * 4 + cb) * 16 + c] = lsum[cb];
    }

    // O: sequential accumulate across waves
    #pragma unroll
    for (int ww = 0; ww < 4; ++ww) {
        if (w == ww) {
            #pragma unroll
            for (int db = 0; db < 4; ++db) {
                #pragma unroll
                for (int cb = 0; cb < 4; ++cb) {
                    char* p = Ob + (size_t)(((db * 4 + cb) * 4 + quad) * 16 + c) * 16;
                    f32x4 v = o[db][cb];
                    if (ww > 0) v += *(const f32x4*)p;
                    *(f32x4*)p = v;
                }
            }
        }
        __syncthreads();
    }

    // readout: thread t -> q-row n_loc = t&63, d-quarter dq = t>>6
    {
        const int n_loc = tid & 63;
        const int dq    = tid >> 6;
        const int qcb   = n_loc >> 4;
        const int cc    = n_loc & 15;
        float l = Lb[(0 * 4 + qcb) * 16 + cc] + Lb[(1 * 4 + qcb) * 16 + cc]
                + Lb[(2 * 4 + qcb) * 16 + cc] + Lb[(3 * 4 + qcb) * 16 + cc];
        float inv = 1.0f / l;
        float vals[16];
        #pragma unroll
        for (int q2 = 0; q2 < 4; ++q2) {
            f32x4 v = *(const f32x4*)(Ob
                    + (size_t)(((dq * 4 + qcb) * 4 + q2) * 16 + cc) * 16);
            vals[q2 * 4 + 0] = v[0]; vals[q2 * 4 + 1] = v[1];
            vals[q2 * 4 + 2] = v[2]; vals[q2 * 4 + 3] = v[3];
        }
        bf16x8 o0, o1;
        #pragma unroll
        for (int j = 0; j < 8; ++j) {
            o0[j] = (bf16_t)(vals[j] * inv);
            o1[j] = (bf16_t)(vals[8 + j] * inv);
        }
        bf16_t* yrow = y + bh * (size_t)(NN * DD) + (size_t)(n0 + n_loc) * DD + dq * 16;
        *(bf16x8*)(yrow)     = o0;
        *(bf16x8*)(yrow + 8) = o1;
    }
}

// -------------------------------------------------------------------------
// Kernel C: output projection via MFMA (unchanged). 512 blocks.
// -------------------------------------------------------------------------
__global__ __launch_bounds__(256) void out_proj(
    const bf16_t* __restrict__ y,    // [b,h,n,d] bf16
    const bf16_t* __restrict__ Wut,  // [64][512]
    const float* __restrict__ bu, float* __restrict__ out)
{
    const int rt   = blockIdx.x >> 1;
    const int dh   = blockIdx.x & 1;
    const int row0 = rt * 32;
    const int b    = row0 >> 11;
    const int nn0  = row0 & 2047;
    const int tid  = threadIdx.x;
    const int w    = tid >> 6;
    const int lane = tid & 63;
    const int quad = lane >> 4;
    const int c    = lane & 15;
    const int cq   = c & 7;

    __shared__ __align__(16) bf16_t ys[32 * 512];   // 32KB [row][1024B], swizzled

    {
        const int hsel = lane >> 3;
        const int g7   = lane & 7;
        #pragma unroll
        for (int rr = 0; rr < 8; ++rr) {
            int row = w * 8 + rr;
            const char* src = (const char*)y
                + (((size_t)b * HH + hsel) * NN + nn0 + row) * 128
                + ((g7 ^ (row & 7)) * 16);
            dma16(src, (char*)ys + row * 1024);
        }
    }
    __syncthreads();

    const int rows16 = (w >> 1) * 16;
    const int mb     = dh * 2 + (w & 1);
    const char* yrow = (const char*)ys + (rows16 + c) * 1024;

    f32x4 acc = (f32x4){0.f, 0.f, 0.f, 0.f};
    #pragma unroll
    for (int kk = 0; kk < 16; ++kk) {
        int g = kk * 4 + quad;
        bf16x8 bfrag = *(const bf16x8*)(yrow + (((g & ~7) | ((g & 7) ^ cq)) * 16));
        bf16x8 afrag = *(const bf16x8*)((const char*)Wut
                        + (size_t)(mb * 16 + c) * 1024 + kk * 64 + quad * 16);
        acc = MFMA(afrag, bfrag, acc, 0, 0, 0);
    }

    float4 bb = *(const float4*)(bu + mb * 16 + quad * 4);
    float4 res = { acc[0] + bb.x, acc[1] + bb.y, acc[2] + bb.z, acc[3] + bb.w };
    float* op = out + (size_t)(row0 + rows16 + c) * DD + mb * 16 + quad * 4;
    *(float4*)op = res;
}

// -------------------------------------------------------------------------
extern "C" void kernel_launch(void* const* d_in, const int* in_sizes, int n_in,
                              void* d_out, int out_size, void* d_ws, size_t ws_size,
                              hipStream_t stream) {
    const float* x  = (const float*)d_in[0];
    const float* Wq = (const float*)d_in[1];
    const float* Wk = (const float*)d_in[2];
    const float* Wv = (const float*)d_in[3];
    const float* Wu = (const float*)d_in[4];
    const float* bu = (const float*)d_in[5];
    float* out = (float*)d_out;

    // workspace: q8 4M | k8 4M | vt 8M (f16) | y 8M (bf16) | weights 64K x4
    const size_t SEG8 = (size_t)BB * HH * NN * 64;   // 4 MiB (fp8 rows)
    const size_t SEG  = SEG8 * 2;                    // 8 MiB
    char* ws = (char*)d_ws;
    char*   q8  = ws;
    char*   k8  = ws + SEG8;
    f16_t*  vt  = (f16_t*)(ws + 2 * SEG8);
    bf16_t* y   = (bf16_t*)(ws + 2 * SEG8 + SEG);
    bf16_t* Wqt = (bf16_t*)(ws + 2 * SEG8 + 2 * SEG);
    bf16_t* Wkt = (bf16_t*)(ws + 2 * SEG8 + 2 * SEG + (1 << 16));
    bf16_t* Wvt = (bf16_t*)(ws + 2 * SEG8 + 2 * SEG + 2 * (1 << 16));
    bf16_t* Wut = (bf16_t*)(ws + 2 * SEG8 + 2 * SEG + 3 * (1 << 16));

    prep<<<dim3(16), dim3(256), 0, stream>>>(Wq, Wk, Wv, Wu, Wqt, Wkt, Wvt, Wut);
    qkv_mfma<<<dim3(128, 8), dim3(256), 0, stream>>>(x, Wqt, Wkt, Wvt, q8, k8, vt);
    flash_attn<<<dim3(HH, NN / 64, BB), dim3(256), 0, stream>>>(q8, k8, vt, y);
    out_proj<<<dim3(512), dim3(256), 0, stream>>>(y, Wut, bu, out);
}